// Round 7
// baseline (430.879 us; speedup 1.0000x reference)
//
#include <hip/hip_runtime.h>
#include <math.h>

// GaussianLayer: per row (B=524288): mu=x[0], sigma=exp(0.5*x[1]);
// pdf over xx=-99..99, cumsum over 199 bins. Output (B,199) fp32 = 417 MB.
// Write-bound; roofline ~67 us at the demonstrated 6.26 TB/s fill rate.
//
// R7: PERSISTENT blocks (2048 x 256 rows, 8 chunks of 32 rows) with
// continuous store streaming:
//  - all chunk inputs preloaded at start: no global loads after the first
//    store -> no vmcnt entanglement ever forces a store drain
//  - barriers are raw `s_waitcnt lgkmcnt(0); s_barrier` (LDS-only sync):
//    compiler never emits vmcnt(0)-before-s_barrier, stores stay in flight
//    across chunks
//  - per chunk: segment cumsum in regs -> LDS (flat, == out layout) ->
//    contiguous 16B nt store sweep (25,472 B, 64B-line aligned)

#define NB    199
#define CROWS 32     // rows per chunk
#define NCH   8      // chunks per block -> 256 rows/block
#define NT    256

typedef float fx4 __attribute__((ext_vector_type(4)));

__device__ __forceinline__ void lds_barrier() {
    // LDS-scope workgroup barrier: does NOT drain outstanding global stores.
    asm volatile("s_waitcnt lgkmcnt(0)\n\ts_barrier" ::: "memory");
}

__global__ __launch_bounds__(NT, 4)
void gauss_cdf_kernel(const float2* __restrict__ x, float* __restrict__ out, int B) {
    __shared__ __align__(16) float lds[CROWS * NB];   // 25,472 B
    __shared__ float tot[8 * CROWS];                  // per-segment totals

    const int tid = threadIdx.x;
    const int r   = tid & 31;        // row within chunk
    const int q   = tid >> 5;        // segment 0..7 (25 bins, last 24)
    const long rowBase = (long)blockIdx.x * (CROWS * NCH);
    if (rowBase >= B) return;

    // preload ALL chunk inputs up-front (before any store is issued)
    float2 v[NCH];
    #pragma unroll
    for (int k = 0; k < NCH; ++k) {
        long row = rowBase + (long)k * CROWS + r;
        v[k] = x[row < B ? row : (B - 1)];
    }

    const int qs   = q * 25;
    const int qlen = (q == 7) ? 24 : 25;
    float* dst = lds + r * NB + qs;
    const fx4* src = reinterpret_cast<const fx4*>(lds);

    #pragma unroll 1
    for (int k = 0; k < NCH; ++k) {
        float mu = v[k].x;
        float s  = __expf(-0.5f * v[k].y);       // 1/sigma
        float inv_norm = 0.3989422804014327f * s;
        float coefA    = -0.5f * s * s;
        const float tb = (float)(qs - 99) - mu;

        // segment cumsum in registers
        float c[25];
        float acc = 0.f;
        #pragma unroll
        for (int j = 0; j < 25; ++j) {
            float t = tb + (float)j;
            acc += inv_norm * __expf(coefA * t * t);
            c[j] = acc;
        }
        tot[q * CROWS + r] = acc;
        lds_barrier();

        // prefix of earlier segments, write base-adjusted to LDS
        float base = 0.f;
        #pragma unroll
        for (int kk = 0; kk < 7; ++kk)
            if (kk < q) base += tot[kk * CROWS + r];
        #pragma unroll
        for (int j = 0; j < 25; ++j)
            if (j < qlen) dst[j] = c[j] + base;
        lds_barrier();

        // contiguous nt float4 sweep: 1592 vec4 = 6 full rounds + 56
        fx4* d4 = reinterpret_cast<fx4*>(out + (rowBase + (long)k * CROWS) * NB);
        #pragma unroll
        for (int i = 0; i < 6; ++i)
            __builtin_nontemporal_store(src[tid + i * NT], &d4[tid + i * NT]);
        if (tid < (CROWS * NB / 4) - 6 * NT)   // 1592 - 1536 = 56
            __builtin_nontemporal_store(src[tid + 6 * NT], &d4[tid + 6 * NT]);
        lds_barrier();   // protect LDS reuse; still no store drain
    }
}

extern "C" void kernel_launch(void* const* d_in, const int* in_sizes, int n_in,
                              void* d_out, int out_size, void* d_ws, size_t ws_size,
                              hipStream_t stream) {
    const float2* x = (const float2*)d_in[0];
    float* out = (float*)d_out;
    const int B = in_sizes[0] / 2;                       // 524288
    const int rowsPerBlock = CROWS * NCH;                // 256
    const int grid = (B + rowsPerBlock - 1) / rowsPerBlock;  // 2048
    gauss_cdf_kernel<<<grid, NT, 0, stream>>>(x, out, B);
}